// Round 10
// baseline (151.878 us; speedup 1.0000x reference)
//
#include <hip/hip_runtime.h>
#include <hip/hip_fp16.h>

// Deformable conv B=4 C=64 H=W=128 O=64 3x3 s1 p1 d1, DG=1.
// v10 = v8 skeleton (prep fp16-octet xt + LDS window gather) with the sS
// staging round-trip eliminated: 128-thread blocks, 2 waves; each lane
// samples directly into its own MFMA B-fragment registers (lane (quad,l15)
// at kstep ks consumes octet g=ks*4+quad at wo=nw*16+l15 — exactly the
// octet it gathers). Invalid groups (g>=9) use zeroed blend weights.

#define B_  4
#define C_  64
#define H_  128
#define W_  128
#define O_  64
#define HO_ 128
#define WO_ 128
#define HW_ (H_ * W_)
#define NCHUNK 8
#define NGW 12            // weight K-groups per chunk: 9 real taps + 3 zero
#define KSTEPS 3          // NGW*8 / 32
#define NT_ 32            // wo tile per block
#define TR  16            // tile rows (y in [ho-7, ho+9))
#define TC  48            // tile cols (x in [woB-8, woB+40))
#define TSLOTS (TR * TC)  // 768 positions x 16 B = 12 KB

typedef _Float16 half8 __attribute__((ext_vector_type(8)));
typedef __attribute__((ext_vector_type(4))) float f32x4;

union H8 { float4 v; __half2 h2[4]; half8 v8; __half h[8]; };

// Merged prep: blocks [0,2048) transpose+cvt x -> xt fp16 [B][CH=8][H][W][8ch];
// blocks [2048,2072) build wt fp16 [(ch*12+g)*64+o]*8+e  (g<9: tap g, else 0).
__global__ __launch_bounds__(256)
void prep(const float* __restrict__ x, const float* __restrict__ w,
          __half* __restrict__ xt, __half* __restrict__ wt) {
    const int tid = threadIdx.x;
    if (blockIdx.x < 2048) {
        int t = blockIdx.x * 256 + tid;          // (b,ch,y,x)
        int xc = t & 127;
        int y  = (t >> 7) & 127;
        int ch = (t >> 14) & 7;
        int b  = t >> 17;
        const float* xp = x + (((size_t)(b * C_ + ch * 8) * H_) + y) * W_ + xc;
        union { __half h[8]; float4 v; } pk;
#pragma unroll
        for (int e = 0; e < 8; ++e) pk.h[e] = __float2half_rn(xp[e * HW_]);
        *(float4*)(xt + (size_t)t * 8) = pk.v;
    } else {
        int t = (blockIdx.x - 2048) * 256 + tid;  // (ch,g,o), 6144 total
        if (t >= NCHUNK * NGW * O_) return;
        int o  = t & 63;
        int g  = (t >> 6) % NGW;
        int ch = (t >> 6) / NGW;
        union { __half h[8]; float4 v; } pk;
#pragma unroll
        for (int e = 0; e < 8; ++e)
            pk.h[e] = (g < 9) ? __float2half_rn(w[(o * C_ + ch * 8 + e) * 9 + g])
                              : __half(0.0f);
        *(float4*)(wt + (size_t)t * 8) = pk.v;
    }
}

__global__ __launch_bounds__(128, 4)
void dcn_mfma(const __half* __restrict__ xt, const float* __restrict__ off,
              const __half* __restrict__ wt, const float* __restrict__ bias,
              float* __restrict__ out) {
    __shared__ __align__(16) _Float16 sT[TSLOTS * 8];   // 12 KB x-window tile

    const int tid = threadIdx.x;               // 0..127 (2 waves)
    const int bid = blockIdx.x;                // (b, ho, wo-quarter)
    const int w4  = bid & 3;
    const int ho  = (bid >> 2) & (HO_ - 1);
    const int b   = bid >> 9;
    const int woB = w4 * NT_;
    const int yorg = ho - 7;
    const int xorg = woB - 8;

    const int lane = tid & 63;
    const int nw   = tid >> 6;                 // wave -> wo half of 16
    const int quad = lane >> 4;
    const int l15  = lane & 15;
    const int wo_l = woB + nw * 16 + l15;      // this lane's output column

    // ---- per-lane bilinear metadata for its 3 K-groups (g = j*4 + quad) ----
    int a0_[3], a1_[3], fb_[3];
    __half2 ua2_[3], ub2_[3], va2_[3], vb2_[3];
#pragma unroll
    for (int j = 0; j < 3; ++j) {
        int g = j * 4 + quad;
        int valid = (g < 9);
        int k  = valid ? g : 0;
        int ki = k / 3, kj = k - 3 * ki;
        float oy = off[(((b * 18) + 2 * k    ) * HO_ + ho) * WO_ + wo_l];
        float ox = off[(((b * 18) + 2 * k + 1) * HO_ + ho) * WO_ + wo_l];
        float py = (float)(ho - 1 + ki) + oy;
        float px = (float)(wo_l - 1 + kj) + ox;
        float y0f = floorf(py), x0f = floorf(px);
        int   y0 = (int)y0f,   x0 = (int)x0f;
        float ly = py - y0f,   lx = px - x0f;
        float hy = 1.f - ly,   hx = 1.f - lx;
        int y1 = y0 + 1, x1 = x0 + 1;
        float vy0 = (y0 >= 0 && y0 < H_) ? 1.f : 0.f;
        float vy1 = (y1 >= 0 && y1 < H_) ? 1.f : 0.f;
        float vx0 = (x0 >= 0 && x0 < W_) ? 1.f : 0.f;
        float vx1 = (x1 >= 0 && x1 < W_) ? 1.f : 0.f;
        int cy0 = min(max(y0, 0), H_ - 1), cy1 = min(max(y1, 0), H_ - 1);
        int cx0 = min(max(x0, 0), W_ - 1), cx1 = min(max(x1, 0), W_ - 1);
        int ax  = min(max(x0, 0), W_ - 2);
        float en  = valid ? 1.f : 0.f;         // invalid group -> zero fragment
        float w00 = hy * hx * vy0 * vx0 * en;
        float w01 = hy * lx * vy0 * vx1 * en;
        float w10 = ly * hx * vy1 * vx0 * en;
        float w11 = ly * lx * vy1 * vx1 * en;
        float s0 = (cx0 != ax) ? 1.f : 0.f;
        float s1 = (cx1 != ax) ? 1.f : 0.f;
        int ty0 = cy0 - yorg, ty1 = cy1 - yorg, tx = ax - xorg;
        int fb = ((unsigned)ty0 > (unsigned)(TR - 1)) |
                 ((unsigned)ty1 > (unsigned)(TR - 1)) |
                 ((unsigned)tx  > (unsigned)(TC - 2));
        fb_[j] = valid ? fb : 0;
        a0_[j] = fb ? (cy0 * W_ + ax) : (ty0 * TC + tx);   // global idx if fallback
        a1_[j] = fb ? (cy1 * W_ + ax) : (ty1 * TC + tx);
        ua2_[j] = __float2half2_rn(w00 * (1.f - s0) + w01 * (1.f - s1));
        ub2_[j] = __float2half2_rn(w00 * s0 + w01 * s1);
        va2_[j] = __float2half2_rn(w10 * (1.f - s0) + w11 * (1.f - s1));
        vb2_[j] = __float2half2_rn(w10 * s0 + w11 * s1);
    }

    // ---- stage-slot global offsets (clamped), 6 slots/thread ----
    int gofs[6];
#pragma unroll
    for (int j = 0; j < 6; ++j) {
        int s  = tid + j * 128;
        int rr = s / TC, cc = s - rr * TC;
        int yc = min(max(yorg + rr, 0), H_ - 1);
        int xc = min(max(xorg + cc, 0), W_ - 1);
        gofs[j] = yc * W_ + xc;
    }

    // ---- window prefetch registers ----
    float4 pf[6];
    auto issue = [&](int ch) {
        const float4* xc = (const float4*)(xt + ((size_t)(b * NCHUNK + ch)) * (HW_ * 8));
#pragma unroll
        for (int j = 0; j < 6; ++j) pf[j] = xc[gofs[j]];
    };

    f32x4 acc[4];
#pragma unroll
    for (int ot = 0; ot < 4; ++ot) acc[ot] = (f32x4){0.f, 0.f, 0.f, 0.f};

    issue(0);
    for (int ch = 0; ch < NCHUNK; ++ch) {
        // write the window tile (waits on prefetch issued last chunk)
        float4* tw = (float4*)sT;
#pragma unroll
        for (int j = 0; j < 6; ++j) tw[tid + j * 128] = pf[j];
        __syncthreads();                       // tile ready
        if (ch + 1 < NCHUNK) issue(ch + 1);    // overlap next fetch with gather+MFMA

        // ---- gather + blend directly into B-fragment registers ----
        half8 bf[3];
        const float4* tl = (const float4*)sT;
        const float4* xcg = (const float4*)(xt + ((size_t)(b * NCHUNK + ch)) * (HW_ * 8));
#pragma unroll
        for (int j = 0; j < 3; ++j) {
            H8 q00, q01, q10, q11;
            if (!fb_[j]) {
                q00.v = tl[a0_[j]];  q01.v = tl[a0_[j] + 1];
                q10.v = tl[a1_[j]];  q11.v = tl[a1_[j] + 1];
            } else {   // exact fallback, |offset| beyond window (~never)
                q00.v = xcg[a0_[j]]; q01.v = xcg[a0_[j] + 1];
                q10.v = xcg[a1_[j]]; q11.v = xcg[a1_[j] + 1];
            }
            H8 s;
#pragma unroll
            for (int p = 0; p < 4; ++p) {
                __half2 t0 = __hmul2(ua2_[j], q00.h2[p]);
                t0 = __hfma2(ub2_[j], q01.h2[p], t0);
                t0 = __hfma2(va2_[j], q10.h2[p], t0);
                t0 = __hfma2(vb2_[j], q11.h2[p], t0);
                s.h2[p] = t0;
            }
            bf[j] = s.v8;
        }
        __syncthreads();                       // all gathers done: tile reusable

        // ---- MFMA: 3 ksteps x 4 o-tiles; B from registers, A from global wt ----
        const __half* wc = wt + (size_t)(ch * NGW) * O_ * 8;
#pragma unroll
        for (int ks = 0; ks < KSTEPS; ++ks) {
            int g = ks * 4 + quad;
#pragma unroll
            for (int ot = 0; ot < 4; ++ot) {
                half8 afr = *(const half8*)(wc + (size_t)(g * O_ + ot * 16 + l15) * 8);
                acc[ot] = __builtin_amdgcn_mfma_f32_16x16x32_f16(afr, bf[ks], acc[ot], 0, 0, 0);
            }
        }
    }

    // ---- epilogue: C/D col = l15 (wo), row = quad*4+reg (o) ----
#pragma unroll
    for (int ot = 0; ot < 4; ++ot) {
#pragma unroll
        for (int rg = 0; rg < 4; ++rg) {
            int o = ot * 16 + quad * 4 + rg;
            out[(((size_t)(b * O_ + o)) * HO_ + ho) * WO_ + wo_l] = acc[ot][rg] + bias[o];
        }
    }
}

extern "C" void kernel_launch(void* const* d_in, const int* in_sizes, int n_in,
                              void* d_out, int out_size, void* d_ws, size_t ws_size,
                              hipStream_t stream) {
    const float* x    = (const float*)d_in[0];
    const float* off  = (const float*)d_in[1];
    const float* w    = (const float*)d_in[2];
    const float* bias = (const float*)d_in[3];
    float* out = (float*)d_out;

    __half* wt = (__half*)d_ws;                       // 98304 B
    __half* xt = (__half*)((char*)d_ws + 262144);     // 8 MB

    hipLaunchKernelGGL(prep, dim3(2048 + 24), dim3(256), 0, stream, x, w, xt, wt);
    hipLaunchKernelGGL(dcn_mfma, dim3(B_ * HO_ * (WO_ / NT_)), dim3(128), 0, stream,
                       xt, off, wt, bias, out);
}

// Round 11
// 103.717 us; speedup vs baseline: 1.4644x; 1.4644x over previous
//
#include <hip/hip_runtime.h>
#include <hip/hip_fp16.h>

// Deformable conv B=4 C=64 H=W=128 O=64 3x3 s1 p1 d1, DG=1.
// v11 = v8 (best verified: fp16-octet xt + LDS window + sS-dedup'd gather +
// 2x2 wave MFMA) with (1) TR 16->12: LDS 22.5->19 KB => 8 blocks/CU even
// dispatch, fewer tile writes; (2) prep vectorized 4x along x.
// v10 lesson: register-resident B-frags spill (200 MB scratch) — keep sS.

#define B_  4
#define C_  64
#define H_  128
#define W_  128
#define O_  64
#define HO_ 128
#define WO_ 128
#define HW_ (H_ * W_)
#define NCHUNK 8
#define NGW 12            // weight K-groups per chunk: 9 real taps + 3 zero
#define KSTEPS 3          // NGW*8 / 32
#define NT_ 32            // wo tile per block
#define NTASK (9 * NT_)   // 288 sampling tasks per chunk
#define SG  10            // sS groups per buffer: 9 taps + 1 zero pad
#define SBUF (SG * NT_ * 8)   // halves per buffer (2560 = 5 KB)
#define TR  12            // tile rows (y in [ho-5, ho+7))
#define TC  48            // tile cols (x in [woB-8, woB+40))
#define TSLOTS (TR * TC)  // 576 positions x 16 B = 9 KB

typedef _Float16 half8 __attribute__((ext_vector_type(8)));
typedef __attribute__((ext_vector_type(4))) float f32x4;

union H8 { float4 v; __half2 h2[4]; half8 v8; __half h[8]; };

// Merged prep: blocks [0,512) transpose+cvt x -> xt fp16 [B][CH=8][H][W][8ch]
// (each thread: 4 consecutive x positions); blocks [512,536) build
// wt fp16 [(ch*12+g)*64+o]*8+e  (g<9: tap g, else 0).
__global__ __launch_bounds__(256)
void prep(const float* __restrict__ x, const float* __restrict__ w,
          __half* __restrict__ xt, __half* __restrict__ wt) {
    const int tid = threadIdx.x;
    if (blockIdx.x < 512) {
        int t  = blockIdx.x * 256 + tid;         // (b,ch,y,xg) xg: group of 4
        int xg = t & 31;
        int y  = (t >> 5) & 127;
        int ch = (t >> 12) & 7;
        int b  = t >> 15;
        const float* xp = x + (((size_t)(b * C_ + ch * 8) * H_) + y) * W_ + xg * 4;
        float4 pl[8];
#pragma unroll
        for (int e = 0; e < 8; ++e) pl[e] = *(const float4*)(xp + e * HW_);
        __half* op = xt + ((((size_t)(b * 8 + ch) * H_ + y) * W_) + xg * 4) * 8;
#pragma unroll
        for (int q = 0; q < 4; ++q) {            // 4 x-positions -> 4 octets
            union { __half h[8]; float4 v; } pk;
            const float* f = (const float*)pl;
#pragma unroll
            for (int e = 0; e < 8; ++e) pk.h[e] = __float2half_rn(f[e * 4 + q]);
            *(float4*)(op + q * 8) = pk.v;
        }
    } else {
        int t = (blockIdx.x - 512) * 256 + tid;  // (ch,g,o), 6144 total
        if (t >= NCHUNK * NGW * O_) return;
        int o  = t & 63;
        int g  = (t >> 6) % NGW;
        int ch = (t >> 6) / NGW;
        union { __half h[8]; float4 v; } pk;
#pragma unroll
        for (int e = 0; e < 8; ++e)
            pk.h[e] = (g < 9) ? __float2half_rn(w[(o * C_ + ch * 8 + e) * 9 + g])
                              : __half(0.0f);
        *(float4*)(wt + (size_t)t * 8) = pk.v;
    }
}

__global__ __launch_bounds__(256, 4)
void dcn_mfma(const __half* __restrict__ xt, const float* __restrict__ off,
              const __half* __restrict__ wt, const float* __restrict__ bias,
              float* __restrict__ out) {
    __shared__ __align__(16) _Float16 sS[2 * SBUF];   // 10 KB double-buffered
    __shared__ __align__(16) _Float16 sT[TSLOTS * 8]; // 9 KB x-window tile

    const int tid = threadIdx.x;
    const int bid = blockIdx.x;              // (b, ho, wo-quarter)
    const int w4  = bid & 3;
    const int ho  = (bid >> 2) & (HO_ - 1);
    const int b   = bid >> 9;
    const int woB = w4 * NT_;
    const int yorg = ho - 5;                 // tile origin (row), TR=12
    const int xorg = woB - 8;                // tile origin (col)

    // ---- bilinear metadata per (k, wo_local) task: tile coords + fallback ----
    int ty0_[2], ty1_[2], tx_[2], fb_[2];
    __half2 ua2_[2], ub2_[2], va2_[2], vb2_[2];
#pragma unroll
    for (int r = 0; r < 2; ++r) {
        int task = tid + r * 256;
        int tk = (task < NTASK) ? task : 0;
        int k  = tk >> 5;
        int wo = (tk & (NT_ - 1)) + woB;
        int ki = k / 3, kj = k - 3 * ki;
        float oy = off[(((b * 18) + 2 * k    ) * HO_ + ho) * WO_ + wo];
        float ox = off[(((b * 18) + 2 * k + 1) * HO_ + ho) * WO_ + wo];
        float py = (float)(ho - 1 + ki) + oy;
        float px = (float)(wo - 1 + kj) + ox;
        float y0f = floorf(py), x0f = floorf(px);
        int   y0 = (int)y0f,   x0 = (int)x0f;
        float ly = py - y0f,   lx = px - x0f;
        float hy = 1.f - ly,   hx = 1.f - lx;
        int y1 = y0 + 1, x1 = x0 + 1;
        float vy0 = (y0 >= 0 && y0 < H_) ? 1.f : 0.f;
        float vy1 = (y1 >= 0 && y1 < H_) ? 1.f : 0.f;
        float vx0 = (x0 >= 0 && x0 < W_) ? 1.f : 0.f;
        float vx1 = (x1 >= 0 && x1 < W_) ? 1.f : 0.f;
        int cy0 = min(max(y0, 0), H_ - 1), cy1 = min(max(y1, 0), H_ - 1);
        int cx0 = min(max(x0, 0), W_ - 1), cx1 = min(max(x1, 0), W_ - 1);
        int ax  = min(max(x0, 0), W_ - 2);
        float w00 = hy * hx * vy0 * vx0;
        float w01 = hy * lx * vy0 * vx1;
        float w10 = ly * hx * vy1 * vx0;
        float w11 = ly * lx * vy1 * vx1;
        float s0 = (cx0 != ax) ? 1.f : 0.f;
        float s1 = (cx1 != ax) ? 1.f : 0.f;
        ty0_[r] = cy0 - yorg;
        ty1_[r] = cy1 - yorg;
        tx_[r]  = ax - xorg;
        fb_[r]  = ((unsigned)ty0_[r] > (unsigned)(TR - 1)) |
                  ((unsigned)ty1_[r] > (unsigned)(TR - 1)) |
                  ((unsigned)tx_[r]  > (unsigned)(TC - 2));
        ua2_[r] = __float2half2_rn(w00 * (1.f - s0) + w01 * (1.f - s1));
        ub2_[r] = __float2half2_rn(w00 * s0 + w01 * s1);
        va2_[r] = __float2half2_rn(w10 * (1.f - s0) + w11 * (1.f - s1));
        vb2_[r] = __float2half2_rn(w10 * s0 + w11 * s1);
    }

    // ---- stage-slot global offsets (clamped): slots 0..575, <=3 per thread ----
    int gofs[3];
#pragma unroll
    for (int j = 0; j < 3; ++j) {
        int s  = tid + j * 256;
        int rr = s / TC, cc = s - rr * TC;
        int yc = min(max(yorg + rr, 0), H_ - 1);
        int xc = min(max(xorg + cc, 0), W_ - 1);
        gofs[j] = yc * W_ + xc;               // harmless clamp for s >= TSLOTS
    }

    // zero pad group (group 9) in both sS buffers: 128 dwords each
    if (tid < 128) {
        ((unsigned int*)&sS[9 * NT_ * 8])[tid]        = 0u;
        ((unsigned int*)&sS[SBUF + 9 * NT_ * 8])[tid] = 0u;
    }

    // ---- window prefetch registers ----
    float4 pf0, pf1, pf2;
    auto issue = [&](int ch) {
        const float4* xc = (const float4*)(xt + ((size_t)(b * NCHUNK + ch)) * (HW_ * 8));
        pf0 = xc[gofs[0]];
        pf1 = xc[gofs[1]];
        if (tid < TSLOTS - 512) pf2 = xc[gofs[2]];
    };

    // ---- sample: LDS-window bilinear gather + fp16 blend -> sS[parity] ----
    auto sample = [&](int ch) {
        _Float16* buf = sS + (ch & 1) * SBUF;
        const float4* xcg = (const float4*)(xt + ((size_t)(b * NCHUNK + ch)) * (HW_ * 8));
        const float4* tl  = (const float4*)sT;
#pragma unroll
        for (int r = 0; r < 2; ++r) {
            int task = tid + r * 256;
            if (task < NTASK) {
                int k  = task >> 5;
                int wo = task & (NT_ - 1);
                H8 q00, q01, q10, q11;
                if (!fb_[r]) {
                    int a0 = ty0_[r] * TC + tx_[r];
                    int a1 = ty1_[r] * TC + tx_[r];
                    q00.v = tl[a0];  q01.v = tl[a0 + 1];
                    q10.v = tl[a1];  q11.v = tl[a1 + 1];
                } else {   // exact fallback for taps outside the window (rare)
                    int a0 = (ty0_[r] + yorg) * W_ + (tx_[r] + xorg);
                    int a1 = (ty1_[r] + yorg) * W_ + (tx_[r] + xorg);
                    q00.v = xcg[a0]; q01.v = xcg[a0 + 1];
                    q10.v = xcg[a1]; q11.v = xcg[a1 + 1];
                }
                H8 s;
#pragma unroll
                for (int j = 0; j < 4; ++j) {
                    __half2 t0 = __hmul2(ua2_[r], q00.h2[j]);
                    t0 = __hfma2(ub2_[r], q01.h2[j], t0);
                    t0 = __hfma2(va2_[r], q10.h2[j], t0);
                    t0 = __hfma2(vb2_[r], q11.h2[j], t0);
                    s.h2[j] = t0;
                }
                *(half8*)&buf[(k * NT_ + wo) * 8] = s.v8;
            }
        }
    };

    // ---- GEMM lane mapping: 2x2 wave split ----
    const int lane = tid & 63;
    const int wv   = tid >> 6;
    const int ow   = wv & 1;
    const int nw   = wv >> 1;
    const int quad = lane >> 4;
    const int l15  = lane & 15;

    f32x4 acc[2];
    acc[0] = (f32x4){0.f, 0.f, 0.f, 0.f};
    acc[1] = (f32x4){0.f, 0.f, 0.f, 0.f};

    auto mfma_chunk = [&](int ch) {
        const __half*   wc  = wt + (size_t)(ch * NGW) * O_ * 8;
        const _Float16* buf = sS + (ch & 1) * SBUF;
#pragma unroll
        for (int ks = 0; ks < KSTEPS; ++ks) {
            int g  = ks * 4 + quad;
            int gb = (g < 9) ? g : 9;            // groups 9..11 -> zero pad
            half8 bfr = *(const half8*)&buf[(gb * NT_ + nw * 16 + l15) * 8];
#pragma unroll
            for (int ot = 0; ot < 2; ++ot) {
                half8 afr = *(const half8*)(wc + (size_t)(g * O_ + ow * 32 + ot * 16 + l15) * 8);
                acc[ot] = __builtin_amdgcn_mfma_f32_16x16x32_f16(afr, bfr, acc[ot], 0, 0, 0);
            }
        }
    };

    issue(0);
    for (int ch = 0; ch < NCHUNK; ++ch) {
        // write the x-window tile (waits on the prefetch issued last chunk)
        float4* tw = (float4*)sT;
        tw[tid]       = pf0;
        tw[tid + 256] = pf1;
        if (tid < TSLOTS - 512) tw[tid + 512] = pf2;
        __syncthreads();                       // tile ready; sS[(ch-1)&1] complete
        if (ch + 1 < NCHUNK) issue(ch + 1);    // overlap next window fetch
        sample(ch);                            // LDS gather -> sS[ch&1]
        if (ch > 0) mfma_chunk(ch - 1);        // reads sS[(ch-1)&1], other parity
        __syncthreads();                       // sample done: tile free, sS ready
    }
    mfma_chunk(NCHUNK - 1);

    // ---- epilogue: C/D col = lane&15 (wo), row = quad*4+reg (o) ----
#pragma unroll
    for (int ot = 0; ot < 2; ++ot) {
        int wo = woB + nw * 16 + l15;
#pragma unroll
        for (int rg = 0; rg < 4; ++rg) {
            int o = ow * 32 + ot * 16 + quad * 4 + rg;
            out[(((size_t)(b * O_ + o)) * HO_ + ho) * WO_ + wo] = acc[ot][rg] + bias[o];
        }
    }
}

extern "C" void kernel_launch(void* const* d_in, const int* in_sizes, int n_in,
                              void* d_out, int out_size, void* d_ws, size_t ws_size,
                              hipStream_t stream) {
    const float* x    = (const float*)d_in[0];
    const float* off  = (const float*)d_in[1];
    const float* w    = (const float*)d_in[2];
    const float* bias = (const float*)d_in[3];
    float* out = (float*)d_out;

    __half* wt = (__half*)d_ws;                       // 98304 B
    __half* xt = (__half*)((char*)d_ws + 262144);     // 8 MB

    hipLaunchKernelGGL(prep, dim3(512 + 24), dim3(256), 0, stream, x, w, xt, wt);
    hipLaunchKernelGGL(dcn_mfma, dim3(B_ * HO_ * (WO_ / NT_)), dim3(256), 0, stream,
                       xt, off, wt, bias, out);
}

// Round 12
// 103.514 us; speedup vs baseline: 1.4672x; 1.0020x over previous
//
#include <hip/hip_runtime.h>
#include <hip/hip_fp16.h>

// Deformable conv B=4 C=64 H=W=128 O=64 3x3 s1 p1 d1, DG=1.
// v12 = v11 with a 1-barrier-per-chunk software pipeline: window tile is
// double-buffered (TR=10 rows to fit: 2x7.5 KB tile + 10 KB sS = 25 KB,
// 6 blocks/CU) and the schedule is
//   sample(ch) ; mfma(ch-1) ; tile_write(ch+1) ; barrier ; issue(ch+2)
// every LDS hazard pair is separated by exactly one barrier. Barriers 16->9.

#define B_  4
#define C_  64
#define H_  128
#define W_  128
#define O_  64
#define HO_ 128
#define WO_ 128
#define HW_ (H_ * W_)
#define NCHUNK 8
#define NGW 12            // weight K-groups per chunk: 9 real taps + 3 zero
#define KSTEPS 3          // NGW*8 / 32
#define NT_ 32            // wo tile per block
#define NTASK (9 * NT_)   // 288 sampling tasks per chunk
#define SG  10            // sS groups per buffer: 9 taps + 1 zero pad
#define SBUF (SG * NT_ * 8)   // halves per buffer (2560 = 5 KB)
#define TR  10            // tile rows (y in [ho-4, ho+6))
#define TC  48            // tile cols (x in [woB-8, woB+40))
#define TSLOTS (TR * TC)  // 480 positions x 16 B = 7.5 KB per buffer

typedef _Float16 half8 __attribute__((ext_vector_type(8)));
typedef __attribute__((ext_vector_type(4))) float f32x4;

union H8 { float4 v; __half2 h2[4]; half8 v8; __half h[8]; };

// Merged prep: blocks [0,512) transpose+cvt x -> xt fp16 [B][CH=8][H][W][8ch]
// (each thread: 4 consecutive x positions); blocks [512,536) build
// wt fp16 [(ch*12+g)*64+o]*8+e  (g<9: tap g, else 0).
__global__ __launch_bounds__(256)
void prep(const float* __restrict__ x, const float* __restrict__ w,
          __half* __restrict__ xt, __half* __restrict__ wt) {
    const int tid = threadIdx.x;
    if (blockIdx.x < 512) {
        int t  = blockIdx.x * 256 + tid;         // (b,ch,y,xg) xg: group of 4
        int xg = t & 31;
        int y  = (t >> 5) & 127;
        int ch = (t >> 12) & 7;
        int b  = t >> 15;
        const float* xp = x + (((size_t)(b * C_ + ch * 8) * H_) + y) * W_ + xg * 4;
        float4 pl[8];
#pragma unroll
        for (int e = 0; e < 8; ++e) pl[e] = *(const float4*)(xp + e * HW_);
        __half* op = xt + ((((size_t)(b * 8 + ch) * H_ + y) * W_) + xg * 4) * 8;
#pragma unroll
        for (int q = 0; q < 4; ++q) {            // 4 x-positions -> 4 octets
            union { __half h[8]; float4 v; } pk;
            const float* f = (const float*)pl;
#pragma unroll
            for (int e = 0; e < 8; ++e) pk.h[e] = __float2half_rn(f[e * 4 + q]);
            *(float4*)(op + q * 8) = pk.v;
        }
    } else {
        int t = (blockIdx.x - 512) * 256 + tid;  // (ch,g,o), 6144 total
        if (t >= NCHUNK * NGW * O_) return;
        int o  = t & 63;
        int g  = (t >> 6) % NGW;
        int ch = (t >> 6) / NGW;
        union { __half h[8]; float4 v; } pk;
#pragma unroll
        for (int e = 0; e < 8; ++e)
            pk.h[e] = (g < 9) ? __float2half_rn(w[(o * C_ + ch * 8 + e) * 9 + g])
                              : __half(0.0f);
        *(float4*)(wt + (size_t)t * 8) = pk.v;
    }
}

__global__ __launch_bounds__(256, 4)
void dcn_mfma(const __half* __restrict__ xt, const float* __restrict__ off,
              const __half* __restrict__ wt, const float* __restrict__ bias,
              float* __restrict__ out) {
    __shared__ __align__(16) _Float16 sS[2 * SBUF];          // 10 KB dbuf
    __shared__ __align__(16) _Float16 sT[2 * TSLOTS * 8];    // 15 KB dbuf tile

    const int tid = threadIdx.x;
    const int bid = blockIdx.x;              // (b, ho, wo-quarter)
    const int w4  = bid & 3;
    const int ho  = (bid >> 2) & (HO_ - 1);
    const int b   = bid >> 9;
    const int woB = w4 * NT_;
    const int yorg = ho - 4;                 // tile origin (row), TR=10
    const int xorg = woB - 8;                // tile origin (col)

    // ---- bilinear metadata per (k, wo_local) task: tile coords + fallback ----
    int ty0_[2], ty1_[2], tx_[2], fb_[2];
    __half2 ua2_[2], ub2_[2], va2_[2], vb2_[2];
#pragma unroll
    for (int r = 0; r < 2; ++r) {
        int task = tid + r * 256;
        int tk = (task < NTASK) ? task : 0;
        int k  = tk >> 5;
        int wo = (tk & (NT_ - 1)) + woB;
        int ki = k / 3, kj = k - 3 * ki;
        float oy = off[(((b * 18) + 2 * k    ) * HO_ + ho) * WO_ + wo];
        float ox = off[(((b * 18) + 2 * k + 1) * HO_ + ho) * WO_ + wo];
        float py = (float)(ho - 1 + ki) + oy;
        float px = (float)(wo - 1 + kj) + ox;
        float y0f = floorf(py), x0f = floorf(px);
        int   y0 = (int)y0f,   x0 = (int)x0f;
        float ly = py - y0f,   lx = px - x0f;
        float hy = 1.f - ly,   hx = 1.f - lx;
        int y1 = y0 + 1, x1 = x0 + 1;
        float vy0 = (y0 >= 0 && y0 < H_) ? 1.f : 0.f;
        float vy1 = (y1 >= 0 && y1 < H_) ? 1.f : 0.f;
        float vx0 = (x0 >= 0 && x0 < W_) ? 1.f : 0.f;
        float vx1 = (x1 >= 0 && x1 < W_) ? 1.f : 0.f;
        int cy0 = min(max(y0, 0), H_ - 1), cy1 = min(max(y1, 0), H_ - 1);
        int cx0 = min(max(x0, 0), W_ - 1), cx1 = min(max(x1, 0), W_ - 1);
        int ax  = min(max(x0, 0), W_ - 2);
        float w00 = hy * hx * vy0 * vx0;
        float w01 = hy * lx * vy0 * vx1;
        float w10 = ly * hx * vy1 * vx0;
        float w11 = ly * lx * vy1 * vx1;
        float s0 = (cx0 != ax) ? 1.f : 0.f;
        float s1 = (cx1 != ax) ? 1.f : 0.f;
        ty0_[r] = cy0 - yorg;
        ty1_[r] = cy1 - yorg;
        tx_[r]  = ax - xorg;
        fb_[r]  = ((unsigned)ty0_[r] > (unsigned)(TR - 1)) |
                  ((unsigned)ty1_[r] > (unsigned)(TR - 1)) |
                  ((unsigned)tx_[r]  > (unsigned)(TC - 2));
        ua2_[r] = __float2half2_rn(w00 * (1.f - s0) + w01 * (1.f - s1));
        ub2_[r] = __float2half2_rn(w00 * s0 + w01 * s1);
        va2_[r] = __float2half2_rn(w10 * (1.f - s0) + w11 * (1.f - s1));
        vb2_[r] = __float2half2_rn(w10 * s0 + w11 * s1);
    }

    // ---- stage-slot global offsets (clamped): 480 slots, <=2 per thread ----
    int gofs[2];
#pragma unroll
    for (int j = 0; j < 2; ++j) {
        int s  = tid + j * 256;
        int sc = (s < TSLOTS) ? s : 0;
        int rr = sc / TC, cc = sc - rr * TC;
        int yc = min(max(yorg + rr, 0), H_ - 1);
        int xc = min(max(xorg + cc, 0), W_ - 1);
        gofs[j] = yc * W_ + xc;
    }

    // zero pad group (group 9) in both sS buffers: 128 dwords each
    if (tid < 128) {
        ((unsigned int*)&sS[9 * NT_ * 8])[tid]        = 0u;
        ((unsigned int*)&sS[SBUF + 9 * NT_ * 8])[tid] = 0u;
    }

    // ---- window prefetch registers ----
    float4 pf0, pf1;
    auto issue = [&](int ch) {
        const float4* xc = (const float4*)(xt + ((size_t)(b * NCHUNK + ch)) * (HW_ * 8));
        pf0 = xc[gofs[0]];
        if (tid < TSLOTS - 256) pf1 = xc[gofs[1]];
    };
    auto tile_write = [&](int ch) {          // pf -> tile[ch&1]
        float4* tw = (float4*)(sT + (ch & 1) * (TSLOTS * 8));
        tw[tid] = pf0;
        if (tid < TSLOTS - 256) tw[tid + 256] = pf1;
    };

    // ---- sample: LDS-window bilinear gather + fp16 blend -> sS[ch&1] ----
    auto sample = [&](int ch) {
        _Float16* buf = sS + (ch & 1) * SBUF;
        const float4* xcg = (const float4*)(xt + ((size_t)(b * NCHUNK + ch)) * (HW_ * 8));
        const float4* tl  = (const float4*)(sT + (ch & 1) * (TSLOTS * 8));
#pragma unroll
        for (int r = 0; r < 2; ++r) {
            int task = tid + r * 256;
            if (task < NTASK) {
                int k  = task >> 5;
                int wo = task & (NT_ - 1);
                H8 q00, q01, q10, q11;
                if (!fb_[r]) {
                    int a0 = ty0_[r] * TC + tx_[r];
                    int a1 = ty1_[r] * TC + tx_[r];
                    q00.v = tl[a0];  q01.v = tl[a0 + 1];
                    q10.v = tl[a1];  q11.v = tl[a1 + 1];
                } else {   // exact fallback for taps outside the window (rare)
                    int a0 = (ty0_[r] + yorg) * W_ + (tx_[r] + xorg);
                    int a1 = (ty1_[r] + yorg) * W_ + (tx_[r] + xorg);
                    q00.v = xcg[a0]; q01.v = xcg[a0 + 1];
                    q10.v = xcg[a1]; q11.v = xcg[a1 + 1];
                }
                H8 s;
#pragma unroll
                for (int j = 0; j < 4; ++j) {
                    __half2 t0 = __hmul2(ua2_[r], q00.h2[j]);
                    t0 = __hfma2(ub2_[r], q01.h2[j], t0);
                    t0 = __hfma2(va2_[r], q10.h2[j], t0);
                    t0 = __hfma2(vb2_[r], q11.h2[j], t0);
                    s.h2[j] = t0;
                }
                *(half8*)&buf[(k * NT_ + wo) * 8] = s.v8;
            }
        }
    };

    // ---- GEMM lane mapping: 2x2 wave split ----
    const int lane = tid & 63;
    const int wv   = tid >> 6;
    const int ow   = wv & 1;
    const int nw   = wv >> 1;
    const int quad = lane >> 4;
    const int l15  = lane & 15;

    f32x4 acc[2];
    acc[0] = (f32x4){0.f, 0.f, 0.f, 0.f};
    acc[1] = (f32x4){0.f, 0.f, 0.f, 0.f};

    auto mfma_chunk = [&](int ch) {
        const __half*   wc  = wt + (size_t)(ch * NGW) * O_ * 8;
        const _Float16* buf = sS + (ch & 1) * SBUF;
#pragma unroll
        for (int ks = 0; ks < KSTEPS; ++ks) {
            int g  = ks * 4 + quad;
            int gb = (g < 9) ? g : 9;            // groups 9..11 -> zero pad
            half8 bfr = *(const half8*)&buf[(gb * NT_ + nw * 16 + l15) * 8];
#pragma unroll
            for (int ot = 0; ot < 2; ++ot) {
                half8 afr = *(const half8*)(wc + (size_t)(g * O_ + ow * 32 + ot * 16 + l15) * 8);
                acc[ot] = __builtin_amdgcn_mfma_f32_16x16x32_f16(afr, bfr, acc[ot], 0, 0, 0);
            }
        }
    };

    // ---- pipelined main loop: ONE barrier per chunk ----
    issue(0);
    tile_write(0);           // waits on issue(0) via register dependency
    issue(1);                // WAR on pf: issues after tile_write consumed them
    __syncthreads();         // tile[0] visible to all

    for (int ch = 0; ch < NCHUNK; ++ch) {
        sample(ch);                          // tile[ch&1] -> sS[ch&1]
        if (ch > 0) mfma_chunk(ch - 1);      // sS[(ch-1)&1]
        if (ch + 1 < NCHUNK) tile_write(ch + 1);   // tile[(ch+1)&1]; prev reader
                                                   // sample(ch-1), 1 barrier ago
        __syncthreads();
        if (ch + 2 < NCHUNK) issue(ch + 2);  // full iteration of latency slack
    }
    mfma_chunk(NCHUNK - 1);

    // ---- epilogue: C/D col = lane&15 (wo), row = quad*4+reg (o) ----
#pragma unroll
    for (int ot = 0; ot < 2; ++ot) {
        int wo = woB + nw * 16 + l15;
#pragma unroll
        for (int rg = 0; rg < 4; ++rg) {
            int o = ow * 32 + ot * 16 + quad * 4 + rg;
            out[(((size_t)(b * O_ + o)) * HO_ + ho) * WO_ + wo] = acc[ot][rg] + bias[o];
        }
    }
}

extern "C" void kernel_launch(void* const* d_in, const int* in_sizes, int n_in,
                              void* d_out, int out_size, void* d_ws, size_t ws_size,
                              hipStream_t stream) {
    const float* x    = (const float*)d_in[0];
    const float* off  = (const float*)d_in[1];
    const float* w    = (const float*)d_in[2];
    const float* bias = (const float*)d_in[3];
    float* out = (float*)d_out;

    __half* wt = (__half*)d_ws;                       // 98304 B
    __half* xt = (__half*)((char*)d_ws + 262144);     // 8 MB

    hipLaunchKernelGGL(prep, dim3(512 + 24), dim3(256), 0, stream, x, w, xt, wt);
    hipLaunchKernelGGL(dcn_mfma, dim3(B_ * HO_ * (WO_ / NT_)), dim3(256), 0, stream,
                       xt, off, wt, bias, out);
}

// Round 13
// 101.731 us; speedup vs baseline: 1.4929x; 1.0175x over previous
//
#include <hip/hip_runtime.h>
#include <hip/hip_fp16.h>

// Deformable conv B=4 C=64 H=W=128 O=64 3x3 s1 p1 d1, DG=1.
// v13 = composition of the two best-measured components, nothing else:
//  - dcn: v8 structure verbatim (fp16-octet xt, TR=16x48 LDS window, sS dedup
//    double-buffer, 2x2 wave MFMA, prefetch-ahead issue()) — best dcn (~30 us).
//  - prep: v11's 4x-vectorized transpose (512+24 blocks) — worth ~3-4 us.
// v10/v11/v12 lessons: register-direct B-frags spill; TR shrink + 1-barrier
// pipeline are neutral; keep the simple 2-barrier loop.

#define B_  4
#define C_  64
#define H_  128
#define W_  128
#define O_  64
#define HO_ 128
#define WO_ 128
#define HW_ (H_ * W_)
#define NCHUNK 8
#define NGW 12            // weight K-groups per chunk: 9 real taps + 3 zero
#define KSTEPS 3          // NGW*8 / 32
#define NT_ 32            // wo tile per block
#define NTASK (9 * NT_)   // 288 sampling tasks per chunk
#define SG  10            // sS groups per buffer: 9 taps + 1 zero pad
#define SBUF (SG * NT_ * 8)   // halves per buffer (2560 = 5 KB)
#define TR  16            // tile rows (y in [ho-7, ho+9))
#define TC  48            // tile cols (x in [woB-8, woB+40))
#define TSLOTS (TR * TC)  // 768 positions x 16 B = 12 KB

typedef _Float16 half8 __attribute__((ext_vector_type(8)));
typedef __attribute__((ext_vector_type(4))) float f32x4;

union H8 { float4 v; __half2 h2[4]; half8 v8; __half h[8]; };

// Merged prep: blocks [0,512) transpose+cvt x -> xt fp16 [B][CH=8][H][W][8ch]
// (each thread: 4 consecutive x positions); blocks [512,536) build
// wt fp16 [(ch*12+g)*64+o]*8+e  (g<9: tap g, else 0).
__global__ __launch_bounds__(256)
void prep(const float* __restrict__ x, const float* __restrict__ w,
          __half* __restrict__ xt, __half* __restrict__ wt) {
    const int tid = threadIdx.x;
    if (blockIdx.x < 512) {
        int t  = blockIdx.x * 256 + tid;         // (b,ch,y,xg) xg: group of 4
        int xg = t & 31;
        int y  = (t >> 5) & 127;
        int ch = (t >> 12) & 7;
        int b  = t >> 15;
        const float* xp = x + (((size_t)(b * C_ + ch * 8) * H_) + y) * W_ + xg * 4;
        float4 pl[8];
#pragma unroll
        for (int e = 0; e < 8; ++e) pl[e] = *(const float4*)(xp + e * HW_);
        __half* op = xt + ((((size_t)(b * 8 + ch) * H_ + y) * W_) + xg * 4) * 8;
#pragma unroll
        for (int q = 0; q < 4; ++q) {            // 4 x-positions -> 4 octets
            union { __half h[8]; float4 v; } pk;
            const float* f = (const float*)pl;
#pragma unroll
            for (int e = 0; e < 8; ++e) pk.h[e] = __float2half_rn(f[e * 4 + q]);
            *(float4*)(op + q * 8) = pk.v;
        }
    } else {
        int t = (blockIdx.x - 512) * 256 + tid;  // (ch,g,o), 6144 total
        if (t >= NCHUNK * NGW * O_) return;
        int o  = t & 63;
        int g  = (t >> 6) % NGW;
        int ch = (t >> 6) / NGW;
        union { __half h[8]; float4 v; } pk;
#pragma unroll
        for (int e = 0; e < 8; ++e)
            pk.h[e] = (g < 9) ? __float2half_rn(w[(o * C_ + ch * 8 + e) * 9 + g])
                              : __half(0.0f);
        *(float4*)(wt + (size_t)t * 8) = pk.v;
    }
}

__global__ __launch_bounds__(256, 4)
void dcn_mfma(const __half* __restrict__ xt, const float* __restrict__ off,
              const __half* __restrict__ wt, const float* __restrict__ bias,
              float* __restrict__ out) {
    __shared__ __align__(16) _Float16 sS[2 * SBUF];   // 10 KB double-buffered
    __shared__ __align__(16) _Float16 sT[TSLOTS * 8]; // 12 KB x-window tile

    const int tid = threadIdx.x;
    const int bid = blockIdx.x;              // (b, ho, wo-quarter)
    const int w4  = bid & 3;
    const int ho  = (bid >> 2) & (HO_ - 1);
    const int b   = bid >> 9;
    const int woB = w4 * NT_;
    const int yorg = ho - 7;                 // tile origin (row)
    const int xorg = woB - 8;                // tile origin (col)

    // ---- bilinear metadata per (k, wo_local) task: tile coords + fallback ----
    int ty0_[2], ty1_[2], tx_[2], fb_[2];
    __half2 ua2_[2], ub2_[2], va2_[2], vb2_[2];
#pragma unroll
    for (int r = 0; r < 2; ++r) {
        int task = tid + r * 256;
        int tk = (task < NTASK) ? task : 0;
        int k  = tk >> 5;
        int wo = (tk & (NT_ - 1)) + woB;
        int ki = k / 3, kj = k - 3 * ki;
        float oy = off[(((b * 18) + 2 * k    ) * HO_ + ho) * WO_ + wo];
        float ox = off[(((b * 18) + 2 * k + 1) * HO_ + ho) * WO_ + wo];
        float py = (float)(ho - 1 + ki) + oy;
        float px = (float)(wo - 1 + kj) + ox;
        float y0f = floorf(py), x0f = floorf(px);
        int   y0 = (int)y0f,   x0 = (int)x0f;
        float ly = py - y0f,   lx = px - x0f;
        float hy = 1.f - ly,   hx = 1.f - lx;
        int y1 = y0 + 1, x1 = x0 + 1;
        float vy0 = (y0 >= 0 && y0 < H_) ? 1.f : 0.f;
        float vy1 = (y1 >= 0 && y1 < H_) ? 1.f : 0.f;
        float vx0 = (x0 >= 0 && x0 < W_) ? 1.f : 0.f;
        float vx1 = (x1 >= 0 && x1 < W_) ? 1.f : 0.f;
        int cy0 = min(max(y0, 0), H_ - 1), cy1 = min(max(y1, 0), H_ - 1);
        int cx0 = min(max(x0, 0), W_ - 1), cx1 = min(max(x1, 0), W_ - 1);
        int ax  = min(max(x0, 0), W_ - 2);
        float w00 = hy * hx * vy0 * vx0;
        float w01 = hy * lx * vy0 * vx1;
        float w10 = ly * hx * vy1 * vx0;
        float w11 = ly * lx * vy1 * vx1;
        float s0 = (cx0 != ax) ? 1.f : 0.f;
        float s1 = (cx1 != ax) ? 1.f : 0.f;
        ty0_[r] = cy0 - yorg;
        ty1_[r] = cy1 - yorg;
        tx_[r]  = ax - xorg;
        fb_[r]  = ((unsigned)ty0_[r] > (unsigned)(TR - 1)) |
                  ((unsigned)ty1_[r] > (unsigned)(TR - 1)) |
                  ((unsigned)tx_[r]  > (unsigned)(TC - 2));
        ua2_[r] = __float2half2_rn(w00 * (1.f - s0) + w01 * (1.f - s1));
        ub2_[r] = __float2half2_rn(w00 * s0 + w01 * s1);
        va2_[r] = __float2half2_rn(w10 * (1.f - s0) + w11 * (1.f - s1));
        vb2_[r] = __float2half2_rn(w10 * s0 + w11 * s1);
    }

    // ---- stage-slot global offsets (clamped), 3 slots/thread ----
    int gofs[3];
#pragma unroll
    for (int j = 0; j < 3; ++j) {
        int s  = tid + j * 256;
        int rr = s / TC, cc = s - rr * TC;
        int yc = min(max(yorg + rr, 0), H_ - 1);
        int xc = min(max(xorg + cc, 0), W_ - 1);
        gofs[j] = yc * W_ + xc;
    }

    // zero pad group (group 9) in both sS buffers: 128 dwords each
    if (tid < 128) {
        ((unsigned int*)&sS[9 * NT_ * 8])[tid]        = 0u;
        ((unsigned int*)&sS[SBUF + 9 * NT_ * 8])[tid] = 0u;
    }

    // ---- window prefetch registers ----
    float4 pf0, pf1, pf2;
    auto issue = [&](int ch) {
        const float4* xc = (const float4*)(xt + ((size_t)(b * NCHUNK + ch)) * (HW_ * 8));
        pf0 = xc[gofs[0]];
        pf1 = xc[gofs[1]];
        pf2 = xc[gofs[2]];
    };

    // ---- sample: LDS-window bilinear gather + fp16 blend -> sS[parity] ----
    auto sample = [&](int ch) {
        _Float16* buf = sS + (ch & 1) * SBUF;
        const float4* xcg = (const float4*)(xt + ((size_t)(b * NCHUNK + ch)) * (HW_ * 8));
        const float4* tl  = (const float4*)sT;
#pragma unroll
        for (int r = 0; r < 2; ++r) {
            int task = tid + r * 256;
            if (task < NTASK) {
                int k  = task >> 5;
                int wo = task & (NT_ - 1);
                H8 q00, q01, q10, q11;
                if (!fb_[r]) {
                    int a0 = ty0_[r] * TC + tx_[r];
                    int a1 = ty1_[r] * TC + tx_[r];
                    q00.v = tl[a0];  q01.v = tl[a0 + 1];
                    q10.v = tl[a1];  q11.v = tl[a1 + 1];
                } else {   // exact fallback for taps outside the window (rare)
                    int a0 = (ty0_[r] + yorg) * W_ + (tx_[r] + xorg);
                    int a1 = (ty1_[r] + yorg) * W_ + (tx_[r] + xorg);
                    q00.v = xcg[a0]; q01.v = xcg[a0 + 1];
                    q10.v = xcg[a1]; q11.v = xcg[a1 + 1];
                }
                H8 s;
#pragma unroll
                for (int j = 0; j < 4; ++j) {
                    __half2 t0 = __hmul2(ua2_[r], q00.h2[j]);
                    t0 = __hfma2(ub2_[r], q01.h2[j], t0);
                    t0 = __hfma2(va2_[r], q10.h2[j], t0);
                    t0 = __hfma2(vb2_[r], q11.h2[j], t0);
                    s.h2[j] = t0;
                }
                *(half8*)&buf[(k * NT_ + wo) * 8] = s.v8;
            }
        }
    };

    // ---- GEMM lane mapping: 2x2 wave split ----
    const int lane = tid & 63;
    const int wv   = tid >> 6;
    const int ow   = wv & 1;
    const int nw   = wv >> 1;
    const int quad = lane >> 4;
    const int l15  = lane & 15;

    f32x4 acc[2];
    acc[0] = (f32x4){0.f, 0.f, 0.f, 0.f};
    acc[1] = (f32x4){0.f, 0.f, 0.f, 0.f};

    auto mfma_chunk = [&](int ch) {
        const __half*   wc  = wt + (size_t)(ch * NGW) * O_ * 8;
        const _Float16* buf = sS + (ch & 1) * SBUF;
#pragma unroll
        for (int ks = 0; ks < KSTEPS; ++ks) {
            int g  = ks * 4 + quad;
            int gb = (g < 9) ? g : 9;            // groups 9..11 -> zero pad
            half8 bfr = *(const half8*)&buf[(gb * NT_ + nw * 16 + l15) * 8];
#pragma unroll
            for (int ot = 0; ot < 2; ++ot) {
                half8 afr = *(const half8*)(wc + (size_t)(g * O_ + ow * 32 + ot * 16 + l15) * 8);
                acc[ot] = __builtin_amdgcn_mfma_f32_16x16x32_f16(afr, bfr, acc[ot], 0, 0, 0);
            }
        }
    };

    issue(0);
    for (int ch = 0; ch < NCHUNK; ++ch) {
        // write the x-window tile (waits on the prefetch issued last chunk)
        float4* tw = (float4*)sT;
        tw[tid]       = pf0;
        tw[tid + 256] = pf1;
        tw[tid + 512] = pf2;
        __syncthreads();                       // tile ready; sS[(ch-1)&1] complete
        if (ch + 1 < NCHUNK) issue(ch + 1);    // overlap next window fetch
        sample(ch);                            // LDS gather -> sS[ch&1]
        if (ch > 0) mfma_chunk(ch - 1);        // reads sS[(ch-1)&1], other parity
        __syncthreads();                       // sample done: tile free, sS ready
    }
    mfma_chunk(NCHUNK - 1);

    // ---- epilogue: C/D col = lane&15 (wo), row = quad*4+reg (o) ----
#pragma unroll
    for (int ot = 0; ot < 2; ++ot) {
        int wo = woB + nw * 16 + l15;
#pragma unroll
        for (int rg = 0; rg < 4; ++rg) {
            int o = ow * 32 + ot * 16 + quad * 4 + rg;
            out[(((size_t)(b * O_ + o)) * HO_ + ho) * WO_ + wo] = acc[ot][rg] + bias[o];
        }
    }
}

extern "C" void kernel_launch(void* const* d_in, const int* in_sizes, int n_in,
                              void* d_out, int out_size, void* d_ws, size_t ws_size,
                              hipStream_t stream) {
    const float* x    = (const float*)d_in[0];
    const float* off  = (const float*)d_in[1];
    const float* w    = (const float*)d_in[2];
    const float* bias = (const float*)d_in[3];
    float* out = (float*)d_out;

    __half* wt = (__half*)d_ws;                       // 98304 B
    __half* xt = (__half*)((char*)d_ws + 262144);     // 8 MB

    hipLaunchKernelGGL(prep, dim3(512 + 24), dim3(256), 0, stream, x, w, xt, wt);
    hipLaunchKernelGGL(dcn_mfma, dim3(B_ * HO_ * (WO_ / NT_)), dim3(256), 0, stream,
                       xt, off, wt, bias, out);
}